// Round 1
// baseline (197.804 us; speedup 1.0000x reference)
//
#include <hip/hip_runtime.h>

// SSIM (win=11, sigma=1.5, data_range=255) fused kernel for N=16,C=3,H=W=512.
// One block = 64x16 output tile; loops the 3 channels internally, accumulating
// per-pixel SSIM, then writes 1 - mean_c(ssim).
//
// Structure per channel:
//   stage1: global -> LDS stage of 74x26 X and Y tiles
//   stage2: vertical 11-tap blur of {x, y, x^2, y^2, xy} -> 5 LDS arrays (74x16)
//           (4-row sliding window in registers: 14 LDS reads feed 4 outputs)
//   stage3: horizontal 11-tap blur + SSIM math (4-col sliding window per thread)
//
// LDS stride padded to 77 (odd): stage-3 lanes are 4 rows x 16 col-groups with
// col stride 4; odd stride maps each row-group to a disjoint bank residue
// class mod 4 -> 2 lanes/bank (free per m136).

namespace {

constexpr int NN = 16, CC = 3, HH = 512, WW = 512;
constexpr int OH = HH - 10, OW = WW - 10;          // 502 x 502
constexpr int TW = 64, TH = 16;                    // output tile
constexpr int RW = TW + 10, RH = TH + 10;          // staged region 74 x 26
constexpr int PAD = 77;                            // LDS row stride (floats)
constexpr float C1c = 6.5025f;                     // (0.01*255)^2
constexpr float C2c = 58.5225f;                    // (0.03*255)^2

__global__ __launch_bounds__(256, 2)
void ssim_kernel(const float* __restrict__ X, const float* __restrict__ Y,
                 float* __restrict__ out)
{
    __shared__ float s_inx[RH][PAD];
    __shared__ float s_iny[RH][PAD];
    __shared__ float s_vx [TH][PAD];
    __shared__ float s_vy [TH][PAD];
    __shared__ float s_vxx[TH][PAD];
    __shared__ float s_vyy[TH][PAD];
    __shared__ float s_vxy[TH][PAD];

    const int tid  = threadIdx.x;
    const int col0 = blockIdx.x * TW;
    const int row0 = blockIdx.y * TH;
    const int n    = blockIdx.z;

    // Gaussian window, computed once per thread (matches jnp float32 math
    // closely enough: normalized, ~1 ulp exp error).
    float w[11];
    {
        float s = 0.f;
        #pragma unroll
        for (int i = 0; i < 11; ++i) {
            float d = (float)(i - 5);
            float g = expf(-d * d * (1.0f / 4.5f));
            w[i] = g; s += g;
        }
        float inv = 1.f / s;
        #pragma unroll
        for (int i = 0; i < 11; ++i) w[i] *= inv;
    }

    // stage-3 mapping: 16 rows x 16 groups of 4 consecutive output cols
    const int r3 = tid >> 4;
    const int c3 = (tid & 15) * 4;

    float acc[4] = {0.f, 0.f, 0.f, 0.f};   // per-pixel SSIM sum over channels

    const size_t plane = (size_t)HH * WW;
    const float* Xn = X + (size_t)n * CC * plane;
    const float* Yn = Y + (size_t)n * CC * plane;

    for (int ch = 0; ch < CC; ++ch) {
        const float* Xc = Xn + (size_t)ch * plane;
        const float* Yc = Yn + (size_t)ch * plane;

        // ---- stage 1: stage input tiles (clamped loads; clamped values only
        // feed outputs that are guarded off at the write) ----
        for (int i = tid; i < RH * RW; i += 256) {
            int r = i / RW, c = i - r * RW;
            int gh = row0 + r; gh = gh < HH ? gh : HH - 1;
            int gw = col0 + c; gw = gw < WW ? gw : WW - 1;
            size_t idx = (size_t)gh * WW + gw;
            s_inx[r][c] = Xc[idx];
            s_iny[r][c] = Yc[idx];
        }
        __syncthreads();

        // ---- stage 2: vertical blur, 4-row sliding windows ----
        for (int i = tid; i < 4 * RW; i += 256) {
            int rg = i / RW, c = i - rg * RW;
            int rb = rg * 4;
            float ax[14], ay[14];
            #pragma unroll
            for (int j = 0; j < 14; ++j) {
                ax[j] = s_inx[rb + j][c];
                ay[j] = s_iny[rb + j][c];
            }
            #pragma unroll
            for (int rr = 0; rr < 4; ++rr) {
                float sx = 0.f, sy = 0.f, sxx = 0.f, syy = 0.f, sxy = 0.f;
                #pragma unroll
                for (int k = 0; k < 11; ++k) {
                    float a = ax[rr + k], b = ay[rr + k], wk = w[k];
                    sx  += wk * a;
                    sy  += wk * b;
                    sxx += wk * a * a;
                    syy += wk * b * b;
                    sxy += wk * a * b;
                }
                s_vx [rb + rr][c] = sx;
                s_vy [rb + rr][c] = sy;
                s_vxx[rb + rr][c] = sxx;
                s_vyy[rb + rr][c] = syy;
                s_vxy[rb + rr][c] = sxy;
            }
        }
        __syncthreads();

        // ---- stage 3: horizontal blur + SSIM ----
        {
            float t[14];
            float mu1[4] = {0,0,0,0}, mu2[4] = {0,0,0,0};
            float exx[4] = {0,0,0,0}, eyy[4] = {0,0,0,0}, exy[4] = {0,0,0,0};

            #pragma unroll
            for (int j = 0; j < 14; ++j) t[j] = s_vx[r3][c3 + j];
            #pragma unroll
            for (int p = 0; p < 4; ++p)
                #pragma unroll
                for (int k = 0; k < 11; ++k) mu1[p] += w[k] * t[p + k];

            #pragma unroll
            for (int j = 0; j < 14; ++j) t[j] = s_vy[r3][c3 + j];
            #pragma unroll
            for (int p = 0; p < 4; ++p)
                #pragma unroll
                for (int k = 0; k < 11; ++k) mu2[p] += w[k] * t[p + k];

            #pragma unroll
            for (int j = 0; j < 14; ++j) t[j] = s_vxx[r3][c3 + j];
            #pragma unroll
            for (int p = 0; p < 4; ++p)
                #pragma unroll
                for (int k = 0; k < 11; ++k) exx[p] += w[k] * t[p + k];

            #pragma unroll
            for (int j = 0; j < 14; ++j) t[j] = s_vyy[r3][c3 + j];
            #pragma unroll
            for (int p = 0; p < 4; ++p)
                #pragma unroll
                for (int k = 0; k < 11; ++k) eyy[p] += w[k] * t[p + k];

            #pragma unroll
            for (int j = 0; j < 14; ++j) t[j] = s_vxy[r3][c3 + j];
            #pragma unroll
            for (int p = 0; p < 4; ++p)
                #pragma unroll
                for (int k = 0; k < 11; ++k) exy[p] += w[k] * t[p + k];

            #pragma unroll
            for (int p = 0; p < 4; ++p) {
                float m1 = mu1[p], m2 = mu2[p];
                float m1s = m1 * m1, m2s = m2 * m2, m12 = m1 * m2;
                float s1  = exx[p] - m1s;
                float s2  = eyy[p] - m2s;
                float s12 = exy[p] - m12;
                float cs  = (2.f * s12 + C2c) / (s1 + s2 + C2c);
                float ss  = (2.f * m12 + C1c) / (m1s + m2s + C1c) * cs;
                acc[p] += ss;
            }
        }
        __syncthreads();   // protect LDS before next channel's stage 1/2
    }

    // ---- epilogue: 1 - mean over channels ----
    const int ho = row0 + r3;
    if (ho < OH) {
        #pragma unroll
        for (int p = 0; p < 4; ++p) {
            int wo = col0 + c3 + p;
            if (wo < OW)
                out[((size_t)n * OH + ho) * OW + wo] = 1.f - acc[p] * (1.f / 3.f);
        }
    }
}

} // namespace

extern "C" void kernel_launch(void* const* d_in, const int* in_sizes, int n_in,
                              void* d_out, int out_size, void* d_ws, size_t ws_size,
                              hipStream_t stream) {
    const float* X = (const float*)d_in[0];
    const float* Y = (const float*)d_in[1];
    float* out = (float*)d_out;

    dim3 grid((OW + TW - 1) / TW,   // 8
              (OH + TH - 1) / TH,   // 32
              NN);                  // 16
    ssim_kernel<<<grid, 256, 0, stream>>>(X, Y, out);
}

// Round 2
// 187.807 us; speedup vs baseline: 1.0532x; 1.0532x over previous
//
#include <hip/hip_runtime.h>

// SSIM (win=11, sigma=1.5, data_range=255) fused kernel for N=16,C=3,H=W=512.
// One block = 64x16 output tile; loops 3 channels internally, accumulating
// per-pixel SSIM, writes 1 - mean_c(ssim).
//
// R2 changes vs R1 (VALU-bound, 63% busy, 3x inst bloat):
//  - compile-time Gaussian weights (SGPR operands, no expf)
//  - stage2 hoists x^2/y^2/xy out of the tap loop (7 -> 5 ops/tap)
//  - PAD=76 (16B-aligned rows) enabling ds_read_b128 in stage3 and
//    float4 global loads + ds_write_b128 in stage1 (fast path, blocks x<7)
//  - single v_rcp_f32 per pixel-channel: (n1*n2)*rcp(d1*d2)
//  - float2 output stores (8B-aligned; OW=502 breaks 16B row alignment)

namespace {

constexpr int NN = 16, CC = 3, HH = 512, WW = 512;
constexpr int OH = HH - 10, OW = WW - 10;          // 502 x 502
constexpr int TW = 64, TH = 16;                    // output tile
constexpr int RW = TW + 10, RH = TH + 10;          // staged region 74 x 26
constexpr int PAD = 76;                            // LDS row stride, 16B-mult
constexpr float C1c = 6.5025f;                     // (0.01*255)^2
constexpr float C2c = 58.5225f;                    // (0.03*255)^2

// _fspecial_gauss_1d(11, 1.5), normalized; matches fp32 reference to ~1 ulp.
__device__ constexpr float W[11] = {
    0.00102838f, 0.00759876f, 0.03600077f, 0.10936069f, 0.21300553f,
    0.26601172f,
    0.21300553f, 0.10936069f, 0.03600077f, 0.00759876f, 0.00102838f
};

__device__ inline void load16(const float* __restrict__ p, float t[16]) {
    float4 a = *(const float4*)(p);
    float4 b = *(const float4*)(p + 4);
    float4 c = *(const float4*)(p + 8);
    float4 d = *(const float4*)(p + 12);
    t[0]=a.x;  t[1]=a.y;  t[2]=a.z;  t[3]=a.w;
    t[4]=b.x;  t[5]=b.y;  t[6]=b.z;  t[7]=b.w;
    t[8]=c.x;  t[9]=c.y;  t[10]=c.z; t[11]=c.w;
    t[12]=d.x; t[13]=d.y; t[14]=d.z; t[15]=d.w;
}

__device__ inline void hconv(const float t[16], float o[4]) {
    #pragma unroll
    for (int p = 0; p < 4; ++p) {
        float s = 0.f;
        #pragma unroll
        for (int k = 0; k < 11; ++k) s = fmaf(W[k], t[p + k], s);
        o[p] = s;
    }
}

__global__ __launch_bounds__(256, 3)
void ssim_kernel(const float* __restrict__ X, const float* __restrict__ Y,
                 float* __restrict__ out)
{
    __shared__ __align__(16) float s_inx[RH][PAD];
    __shared__ __align__(16) float s_iny[RH][PAD];
    __shared__ __align__(16) float s_vx [TH][PAD];
    __shared__ __align__(16) float s_vy [TH][PAD];
    __shared__ __align__(16) float s_vxx[TH][PAD];
    __shared__ __align__(16) float s_vyy[TH][PAD];
    __shared__ __align__(16) float s_vxy[TH][PAD];

    const int tid  = threadIdx.x;
    const int col0 = blockIdx.x * TW;
    const int row0 = blockIdx.y * TH;
    const int n    = blockIdx.z;

    // stage-3 mapping: 16 rows x 16 groups of 4 consecutive output cols
    const int r3 = tid >> 4;
    const int c3 = (tid & 15) * 4;

    float acc[4] = {0.f, 0.f, 0.f, 0.f};

    const size_t plane = (size_t)HH * WW;
    const float* Xn = X + (size_t)n * CC * plane;
    const float* Yn = Y + (size_t)n * CC * plane;
    const bool fastcol = (col0 + 76 <= WW);   // blocks x=0..6

    for (int ch = 0; ch < CC; ++ch) {
        const float* Xc = Xn + (size_t)ch * plane;
        const float* Yc = Yn + (size_t)ch * plane;

        // ---- stage 1: global -> LDS ----
        if (fastcol) {
            // 26 rows x 19 float4 chunks = 494 items (stage 76 cols; extra 2
            // are in-bounds globally and within PAD, never read by compute)
            for (int i = tid; i < RH * 19; i += 256) {
                int r = i / 19, c4 = (i - r * 19) * 4;
                int gh = row0 + r; gh = gh < HH ? gh : HH - 1;   // y=31 blocks
                const float* px = Xc + (size_t)gh * WW + col0 + c4;
                const float* py = Yc + (size_t)gh * WW + col0 + c4;
                float4 vx = *(const float4*)px;
                float4 vy = *(const float4*)py;
                *(float4*)&s_inx[r][c4] = vx;
                *(float4*)&s_iny[r][c4] = vy;
            }
        } else {
            for (int i = tid; i < RH * RW; i += 256) {
                int r = i / RW, c = i - r * RW;
                int gh = row0 + r; gh = gh < HH ? gh : HH - 1;
                int gw = col0 + c; gw = gw < WW ? gw : WW - 1;
                size_t idx = (size_t)gh * WW + gw;
                s_inx[r][c] = Xc[idx];
                s_iny[r][c] = Yc[idx];
            }
        }
        __syncthreads();

        // ---- stage 2: vertical blur, 4-row sliding windows, hoisted squares
        for (int i = tid; i < 4 * RW; i += 256) {
            int rg = i / RW, c = i - rg * RW;
            int rb = rg * 4;
            float ax[14], ay[14], xx[14], yy[14], xy[14];
            #pragma unroll
            for (int j = 0; j < 14; ++j) {
                ax[j] = s_inx[rb + j][c];
                ay[j] = s_iny[rb + j][c];
            }
            #pragma unroll
            for (int j = 0; j < 14; ++j) {
                xx[j] = ax[j] * ax[j];
                yy[j] = ay[j] * ay[j];
                xy[j] = ax[j] * ay[j];
            }
            #pragma unroll
            for (int rr = 0; rr < 4; ++rr) {
                float sx = 0.f, sy = 0.f, sxx = 0.f, syy = 0.f, sxy = 0.f;
                #pragma unroll
                for (int k = 0; k < 11; ++k) {
                    float wk = W[k];
                    sx  = fmaf(wk, ax[rr + k], sx);
                    sy  = fmaf(wk, ay[rr + k], sy);
                    sxx = fmaf(wk, xx[rr + k], sxx);
                    syy = fmaf(wk, yy[rr + k], syy);
                    sxy = fmaf(wk, xy[rr + k], sxy);
                }
                s_vx [rb + rr][c] = sx;
                s_vy [rb + rr][c] = sy;
                s_vxx[rb + rr][c] = sxx;
                s_vyy[rb + rr][c] = syy;
                s_vxy[rb + rr][c] = sxy;
            }
        }
        __syncthreads();

        // ---- stage 3: horizontal blur (b128 reads) + SSIM ----
        {
            float t[16];
            float mu1[4], mu2[4], exx[4], eyy[4], exy[4];

            load16(&s_vx [r3][c3], t); hconv(t, mu1);
            load16(&s_vy [r3][c3], t); hconv(t, mu2);
            load16(&s_vxx[r3][c3], t); hconv(t, exx);
            load16(&s_vyy[r3][c3], t); hconv(t, eyy);
            load16(&s_vxy[r3][c3], t); hconv(t, exy);

            #pragma unroll
            for (int p = 0; p < 4; ++p) {
                float m1 = mu1[p], m2 = mu2[p];
                float m1s = m1 * m1, m2s = m2 * m2, m12 = m1 * m2;
                float s1  = exx[p] - m1s;
                float s2  = eyy[p] - m2s;
                float s12 = exy[p] - m12;
                float n1 = 2.f * m12 + C1c, d1 = m1s + m2s + C1c;
                float n2 = 2.f * s12 + C2c, d2 = s1 + s2 + C2c;
                acc[p] = fmaf(n1 * n2, __builtin_amdgcn_rcpf(d1 * d2), acc[p]);
            }
        }
        __syncthreads();   // protect LDS before next channel's stage 1/2
    }

    // ---- epilogue: 1 - mean over channels ----
    const int ho = row0 + r3;
    if (ho < OH) {
        const int wo = col0 + c3;
        float r0 = 1.f - acc[0] * (1.f / 3.f);
        float r1 = 1.f - acc[1] * (1.f / 3.f);
        float r2 = 1.f - acc[2] * (1.f / 3.f);
        float r3v = 1.f - acc[3] * (1.f / 3.f);
        size_t base = ((size_t)n * OH + ho) * OW + wo;
        if (wo + 3 < OW) {
            // base is even (OW even, wo mult of 4) -> 8B-aligned float2 stores
            *(float2*)(out + base)     = make_float2(r0, r1);
            *(float2*)(out + base + 2) = make_float2(r2, r3v);
        } else {
            float rs[4] = {r0, r1, r2, r3v};
            #pragma unroll
            for (int p = 0; p < 4; ++p)
                if (wo + p < OW) out[base + p] = rs[p];
        }
    }
}

} // namespace

extern "C" void kernel_launch(void* const* d_in, const int* in_sizes, int n_in,
                              void* d_out, int out_size, void* d_ws, size_t ws_size,
                              hipStream_t stream) {
    const float* X = (const float*)d_in[0];
    const float* Y = (const float*)d_in[1];
    float* out = (float*)d_out;

    dim3 grid((OW + TW - 1) / TW,   // 8
              (OH + TH - 1) / TH,   // 32
              NN);                  // 16
    ssim_kernel<<<grid, 256, 0, stream>>>(X, Y, out);
}